// Round 2
// 1450.888 us; speedup vs baseline: 1.0353x; 1.0353x over previous
//
#include <hip/hip_runtime.h>

#define NEG_SLOPE 0.01f
#define CSHIFT 13               // 8192 rows per coarse bucket (<=49 coarse for N<=400k)
#define MSHIFT 7                // 128 rows per mid bucket
#define MPC (1 << (CSHIFT - MSHIFT))   // 64 mids per coarse
#define MWIN 192                // window of mid-counters per split tile (straddle<=2 coarse)
#define CAP 4096                // max edges per mid bucket in csr_sort LDS
#define TILE_E 2048             // edges per split tile

typedef _Float16 half_t;
typedef _Float16 half2_t __attribute__((ext_vector_type(2)));
typedef _Float16 half4_t __attribute__((ext_vector_type(4)));

static inline int cdiv(long long a, long long b) { return (int)((a + b - 1) / b); }

__global__ __launch_bounds__(256) void zero_i32(int* __restrict__ p, int n) {
    int i = blockIdx.x * 256 + threadIdx.x;
    if (i < n) p[i] = 0;
}

// ---- coarse histogram: LDS counters, one merge atomic per (block,bucket) ----
__global__ __launch_bounds__(256) void hist_coarse(const int* __restrict__ rows, int* __restrict__ ccnt, int E) {
    __shared__ int cnt[64];
    int t = threadIdx.x;
    if (t < 64) cnt[t] = 0;
    __syncthreads();
    int base = blockIdx.x * TILE_E;
#pragma unroll
    for (int k = 0; k < TILE_E / 256; k++) {
        int e = base + k * 256 + t;
        if (e < E) atomicAdd(&cnt[rows[e] >> CSHIFT], 1);
    }
    __syncthreads();
    if (t < 64 && cnt[t] > 0) atomicAdd(&ccnt[t], cnt[t]);
}

__global__ void scan_coarse(const int* __restrict__ ccnt, int* __restrict__ cbase,
                            int* __restrict__ cfront, int NBc, int E) {
    if (threadIdx.x == 0 && blockIdx.x == 0) {
        int run = 0;
        for (int b = 0; b < NBc; b++) { cbase[b] = run; cfront[b] = run; run += ccnt[b]; }
        cbase[NBc] = E;
    }
}

// ---- pass A: LDS multisplit into coarse buckets; dense chunk writes ----
// record: ( (row & 8191) << 19 | col , val )   [13+19 = 32 bits exactly, col < 2^19]
__global__ __launch_bounds__(256) void split_coarse(
    const int* __restrict__ rows, const int* __restrict__ cols, const float* __restrict__ vals,
    int* __restrict__ cfront, int2* __restrict__ stg1, int E)
{
    __shared__ int cnt[64], gb[64];
    int t = threadIdx.x;
    if (t < 64) cnt[t] = 0;
    __syncthreads();
    int base = blockIdx.x * TILE_E;
    int myb[8], myrank[8]; int2 mycv[8];
#pragma unroll
    for (int k = 0; k < 8; k++) {
        int e = base + k * 256 + t;
        myb[k] = -1;
        if (e < E) {
            int r = rows[e];
            int b = r >> CSHIFT;
            mycv[k] = make_int2((int)(((unsigned)(r & ((1 << CSHIFT) - 1)) << 19) | (unsigned)cols[e]),
                                __float_as_int(vals[e]));
            myb[k] = b;
            myrank[k] = atomicAdd(&cnt[b], 1);
        }
    }
    __syncthreads();
    if (t < 64 && cnt[t] > 0) gb[t] = atomicAdd(&cfront[t], cnt[t]);
    __syncthreads();
#pragma unroll
    for (int k = 0; k < 8; k++)
        if (myb[k] >= 0) stg1[gb[myb[k]] + myrank[k]] = mycv[k];
}

// ---- mid histogram from coarse-sorted staging (windowed LDS counters) ----
__global__ __launch_bounds__(256) void hist_mid(
    const int2* __restrict__ stg1, const int* __restrict__ cbase_g,
    int* __restrict__ mcnt, int E, int NBc)
{
    __shared__ int cb[66];
    __shared__ int wc[MWIN];
    int t = threadIdx.x;
    for (int i = t; i <= NBc; i += 256) cb[i] = cbase_g[i];
    for (int i = t; i < MWIN; i += 256) wc[i] = 0;
    __syncthreads();
    int base = blockIdx.x * TILE_E;
    int lo = 0, hi = NBc - 1;
    while (lo < hi) { int m = (lo + hi + 1) >> 1; if (cb[m] <= base) lo = m; else hi = m - 1; }
    int winm = lo * MPC;
#pragma unroll
    for (int k = 0; k < 8; k++) {
        int e = base + k * 256 + t;
        if (e < E) {
            int b = lo;
            while (cb[b + 1] <= e) b++;
            int m = b * MPC + (int)(((unsigned)stg1[e].x >> 19) >> MSHIFT);
            int lf = m - winm;
            if (lf >= 0 && lf < MWIN) atomicAdd(&wc[lf], 1);
            else atomicAdd(&mcnt[m], 1);    // rare fallback
        }
    }
    __syncthreads();
    for (int i = t; i < MWIN; i += 256)
        if (wc[i] > 0) atomicAdd(&mcnt[winm + i], wc[i]);
}

// ---- single-block scan over mid buckets (NBm <= 3125) -> mbase, mfront ----
__global__ __launch_bounds__(256) void scan_mid(
    const int* __restrict__ mcnt, int* __restrict__ mbase,
    int* __restrict__ mfront, int NBm, int E)
{
    __shared__ int sd[256];
    __shared__ int carry;
    int t = threadIdx.x;
    if (t == 0) carry = 0;
    __syncthreads();
    for (int base = 0; base < NBm; base += 256) {
        int v = (base + t < NBm) ? mcnt[base + t] : 0;
        sd[t] = v;
        __syncthreads();
        for (int off = 1; off < 256; off <<= 1) {
            int x = (t >= off) ? sd[t - off] : 0;
            __syncthreads();
            sd[t] += x;
            __syncthreads();
        }
        int incl = sd[t] + carry;
        int excl = incl - v;
        if (base + t < NBm) { mbase[base + t] = excl; mfront[base + t] = excl; }
        __syncthreads();
        if (t == 255) carry = incl;
        __syncthreads();
    }
    if (t == 0) mbase[NBm] = E;
}

// ---- pass B: coarse-sorted staging -> mid (128-row) buckets; windowed LDS ranking ----
__global__ __launch_bounds__(256) void split_mid(
    const int2* __restrict__ stg1, const int* __restrict__ cbase_g,
    int* __restrict__ mfront, int2* __restrict__ stgm, int E, int NBc)
{
    __shared__ int cb[66];
    __shared__ int wc[MWIN], wg[MWIN];
    int t = threadIdx.x;
    for (int i = t; i <= NBc; i += 256) cb[i] = cbase_g[i];
    for (int i = t; i < MWIN; i += 256) wc[i] = 0;
    __syncthreads();
    int base = blockIdx.x * TILE_E;
    int lo = 0, hi = NBc - 1;
    while (lo < hi) { int m = (lo + hi + 1) >> 1; if (cb[m] <= base) lo = m; else hi = m - 1; }
    int winm = lo * MPC;
    int mylf[8], myrank[8]; int2 myp[8];
#pragma unroll
    for (int k = 0; k < 8; k++) {
        int e = base + k * 256 + t;
        mylf[k] = -1;
        if (e < E) {
            int b = lo;
            while (cb[b + 1] <= e) b++;
            int2 cv = stg1[e];
            int m = (b << (CSHIFT - MSHIFT)) + (int)(((unsigned)cv.x >> 19) >> MSHIFT);
            int lf = m - winm;
            if (lf >= 0 && lf < MWIN) { mylf[k] = lf; myrank[k] = atomicAdd(&wc[lf], 1); myp[k] = cv; }
            else stgm[atomicAdd(&mfront[m], 1)] = cv;   // rare fallback
        }
    }
    __syncthreads();
    for (int i = t; i < MWIN; i += 256)
        if (wc[i] > 0) wg[i] = atomicAdd(&mfront[winm + i], wc[i]);
    __syncthreads();
#pragma unroll
    for (int k = 0; k < 8; k++)
        if (mylf[k] >= 0) stgm[wg[mylf[k]] + myrank[k]] = myp[k];
}

// ---- pass C: one block per mid bucket; computes its own row counts + rowptr,
//      LDS counting sort to exact CSR; all global writes sequential/dense ----
__global__ __launch_bounds__(256) void csr_sort(
    const int2* __restrict__ stgm, const int* __restrict__ mbase,
    int* __restrict__ rowptr, int2* __restrict__ ecv, int N)
{
    __shared__ int2 buf[CAP];
    __shared__ int cnt[128], sc[128], front[128];
    int mb = blockIdx.x, t = threadIdx.x;
    int row0 = mb << MSHIFT;
    int nrows = N - row0; if (nrows > 128) nrows = 128;
    int s = mbase[mb], eend = mbase[mb + 1];
    if (t < 128) cnt[t] = 0;
    __syncthreads();
    // pass 1: count rows (contiguous L2-resident reads)
    for (int i = s + t; i < eend; i += 256)
        atomicAdd(&cnt[((unsigned)stgm[i].x >> 19) & 127], 1);
    __syncthreads();
    // exclusive scan of 128 counters
    if (t < 128) sc[t] = cnt[t];
    __syncthreads();
    for (int off = 1; off < 128; off <<= 1) {
        int x = (t >= off && t < 128) ? sc[t - off] : 0;
        __syncthreads();
        if (t < 128) sc[t] += x;
        __syncthreads();
    }
    if (t < 128) front[t] = sc[t] - cnt[t];
    if (t < nrows) rowptr[row0 + t] = s + sc[t] - cnt[t];
    if (t == 0 && row0 + nrows == N) rowptr[N] = eend;
    __syncthreads();
    // pass 2: place into LDS at exact local CSR position
    for (int i = s + t; i < eend; i += 256) {
        int2 cv = stgm[i];
        unsigned p = (unsigned)cv.x;
        int rl = ((int)(p >> 19)) & 127;
        int2 rec = make_int2((int)(p & 0x7FFFFu), cv.y);
        int l = atomicAdd(&front[rl], 1);
        if (l < CAP) buf[l] = rec;
        else ecv[s + l] = rec;               // overflow fallback (statistically never)
    }
    __syncthreads();
    int total = eend - s; if (total > CAP) total = CAP;
    for (int l = t; l < total; l += 256) ecv[s + l] = buf[l];
}

// H[n,:] = act(in[n,:]) @ W[0:32,:] + b ;  Z[n,:] = act(in[n,:]) @ W[32:64,:]  (Z stored fp16)
template<int COUT, bool LRELU>
__global__ __launch_bounds__(256) void dense_kernel(
    const float* in, const float* __restrict__ W,
    const float* __restrict__ b, float* H,
    half_t* __restrict__ Z, int N)
{
    int n = blockIdx.x * 256 + threadIdx.x;
    if (n >= N) return;
    const float* row = in + (size_t)n * 32;
    float xv[32];
#pragma unroll
    for (int f = 0; f < 32; f += 4) {
        float4 v = *(const float4*)(row + f);
        xv[f] = v.x; xv[f + 1] = v.y; xv[f + 2] = v.z; xv[f + 3] = v.w;
    }
    if (LRELU) {
#pragma unroll
        for (int f = 0; f < 32; f++) xv[f] = xv[f] > 0.f ? xv[f] : NEG_SLOPE * xv[f];
    }
    float acct[COUT], accb[COUT];
#pragma unroll
    for (int c = 0; c < COUT; c++) { acct[c] = b[c]; accb[c] = 0.f; }
#pragma unroll 4
    for (int f = 0; f < 32; f++) {
        float xf = xv[f];
#pragma unroll
        for (int c = 0; c < COUT; c++) {
            acct[c] = fmaf(xf, W[f * COUT + c], acct[c]);
            accb[c] = fmaf(xf, W[(32 + f) * COUT + c], accb[c]);
        }
    }
    float* hrow = H + (size_t)n * 32;
    half_t* zrow = Z + (size_t)n * 32;
#pragma unroll
    for (int c = 0; c < COUT; c++) hrow[c] = acct[c];
#pragma unroll
    for (int c = 0; c < COUT; c += 2) {
        half2_t h;
        h.x = (half_t)accb[c];
        h.y = (half_t)accb[c + 1];
        *(half2_t*)(zrow + c) = h;
    }
}

// CSR gather, 2 interleaved row-chains per thread (C=32, 8 lanes x half4)
__global__ __launch_bounds__(256) void gather32(
    const int* __restrict__ rowptr, const int2* __restrict__ ecv,
    const half_t* __restrict__ Z, float* __restrict__ H, int N)
{
    int tid = blockIdx.x * 256 + threadIdx.x;
    int pr = tid >> 3, lane = tid & 7;
    int r0 = pr * 2, r1 = r0 + 1;
    if (r0 >= N) return;
    int s0 = rowptr[r0], e0 = rowptr[r0 + 1];
    int s1 = 0, e1 = 0;
    if (r1 < N) { s1 = rowptr[r1]; e1 = rowptr[r1 + 1]; }
    float ax0 = 0.f, ay0 = 0.f, az0 = 0.f, aw0 = 0.f;
    float ax1 = 0.f, ay1 = 0.f, az1 = 0.f, aw1 = 0.f;
    int i0 = s0, i1 = s1;
    while (i0 < e0 && i1 < e1) {
        int2 c0 = ecv[i0]; int2 c1 = ecv[i1];
        half4_t z0 = *(const half4_t*)(Z + (size_t)c0.x * 32 + lane * 4);
        half4_t z1 = *(const half4_t*)(Z + (size_t)c1.x * 32 + lane * 4);
        float v0 = __int_as_float(c0.y), v1 = __int_as_float(c1.y);
        ax0 = fmaf(v0, (float)z0.x, ax0); ay0 = fmaf(v0, (float)z0.y, ay0);
        az0 = fmaf(v0, (float)z0.z, az0); aw0 = fmaf(v0, (float)z0.w, aw0);
        ax1 = fmaf(v1, (float)z1.x, ax1); ay1 = fmaf(v1, (float)z1.y, ay1);
        az1 = fmaf(v1, (float)z1.z, az1); aw1 = fmaf(v1, (float)z1.w, aw1);
        i0++; i1++;
    }
    for (; i0 < e0; i0++) {
        int2 c0 = ecv[i0];
        half4_t z0 = *(const half4_t*)(Z + (size_t)c0.x * 32 + lane * 4);
        float v0 = __int_as_float(c0.y);
        ax0 = fmaf(v0, (float)z0.x, ax0); ay0 = fmaf(v0, (float)z0.y, ay0);
        az0 = fmaf(v0, (float)z0.z, az0); aw0 = fmaf(v0, (float)z0.w, aw0);
    }
    for (; i1 < e1; i1++) {
        int2 c1 = ecv[i1];
        half4_t z1 = *(const half4_t*)(Z + (size_t)c1.x * 32 + lane * 4);
        float v1 = __int_as_float(c1.y);
        ax1 = fmaf(v1, (float)z1.x, ax1); ay1 = fmaf(v1, (float)z1.y, ay1);
        az1 = fmaf(v1, (float)z1.z, az1); aw1 = fmaf(v1, (float)z1.w, aw1);
    }
    float4* hp0 = (float4*)(H + (size_t)r0 * 32 + lane * 4);
    float4 h0 = *hp0;
    h0.x += ax0; h0.y += ay0; h0.z += az0; h0.w += aw0;
    *hp0 = h0;
    if (r1 < N) {
        float4* hp1 = (float4*)(H + (size_t)r1 * 32 + lane * 4);
        float4 h1 = *hp1;
        h1.x += ax1; h1.y += ay1; h1.z += az1; h1.w += aw1;
        *hp1 = h1;
    }
}

// C=10: 2 rows per thread, lanes 0..4 handle half2 each
__global__ __launch_bounds__(256) void gather10(
    const int* __restrict__ rowptr, const int2* __restrict__ ecv,
    const half_t* __restrict__ Z, float* __restrict__ H, int N)
{
    int tid = blockIdx.x * 256 + threadIdx.x;
    int pr = tid >> 3, lane = tid & 7;
    int r0 = pr * 2, r1 = r0 + 1;
    if (r0 >= N || lane >= 5) return;
    int s0 = rowptr[r0], e0 = rowptr[r0 + 1];
    int s1 = 0, e1 = 0;
    if (r1 < N) { s1 = rowptr[r1]; e1 = rowptr[r1 + 1]; }
    float ax0 = 0.f, ay0 = 0.f, ax1 = 0.f, ay1 = 0.f;
    int i0 = s0, i1 = s1;
    while (i0 < e0 && i1 < e1) {
        int2 c0 = ecv[i0]; int2 c1 = ecv[i1];
        half2_t z0 = *(const half2_t*)(Z + (size_t)c0.x * 32 + lane * 2);
        half2_t z1 = *(const half2_t*)(Z + (size_t)c1.x * 32 + lane * 2);
        float v0 = __int_as_float(c0.y), v1 = __int_as_float(c1.y);
        ax0 = fmaf(v0, (float)z0.x, ax0); ay0 = fmaf(v0, (float)z0.y, ay0);
        ax1 = fmaf(v1, (float)z1.x, ax1); ay1 = fmaf(v1, (float)z1.y, ay1);
        i0++; i1++;
    }
    for (; i0 < e0; i0++) {
        int2 c0 = ecv[i0];
        half2_t z0 = *(const half2_t*)(Z + (size_t)c0.x * 32 + lane * 2);
        float v0 = __int_as_float(c0.y);
        ax0 = fmaf(v0, (float)z0.x, ax0); ay0 = fmaf(v0, (float)z0.y, ay0);
    }
    for (; i1 < e1; i1++) {
        int2 c1 = ecv[i1];
        half2_t z1 = *(const half2_t*)(Z + (size_t)c1.x * 32 + lane * 2);
        float v1 = __int_as_float(c1.y);
        ax1 = fmaf(v1, (float)z1.x, ax1); ay1 = fmaf(v1, (float)z1.y, ay1);
    }
    float* hp0 = H + (size_t)r0 * 32 + lane * 2;
    hp0[0] += ax0; hp0[1] += ay0;
    if (r1 < N) {
        float* hp1 = H + (size_t)r1 * 32 + lane * 2;
        hp1[0] += ax1; hp1[1] += ay1;
    }
}

// one block per graph; batch is sorted -> binary search node range, no atomics
__global__ __launch_bounds__(256) void pool_graph(
    const float* __restrict__ H, const int* __restrict__ batch,
    float* __restrict__ pool, int N, int dimoff)
{
    int g = blockIdx.x;
    int lo = 0, hi = N;
    while (lo < hi) { int mid = (lo + hi) >> 1; if (batch[mid] < g) lo = mid + 1; else hi = mid; }
    int start = lo;
    lo = start; hi = N;
    while (lo < hi) { int mid = (lo + hi) >> 1; if (batch[mid] < g + 1) lo = mid + 1; else hi = mid; }
    int end = lo;
    int t = threadIdx.x, f = t & 15, chain = t >> 4;
    __shared__ float sd[256];
    float acc = 0.f;
    if (f < 10) {
        for (int i = start + chain; i < end; i += 16) acc += H[(size_t)i * 32 + f];
    }
    sd[t] = acc; __syncthreads();
    if (chain == 0 && f < 10) {
        float s = 0.f;
#pragma unroll
        for (int k = 0; k < 16; k++) s += sd[k * 16 + f];
        int c = end - start;
        float inv = 1.f / (float)(c > 1 ? c : 1);
        pool[(size_t)g * 30 + dimoff + f] = s * inv;
    }
}

__global__ __launch_bounds__(256) void final_kernel(
    const float* __restrict__ pool, const float* __restrict__ Wf,
    const float* __restrict__ bfv, float* __restrict__ out, int G)
{
    int g = blockIdx.x * 256 + threadIdx.x;
    if (g >= G) return;
    float m[30];
#pragma unroll
    for (int j = 0; j < 30; j++) m[j] = pool[(size_t)g * 30 + j];
    float lg[10];
#pragma unroll
    for (int o = 0; o < 10; o++) {
        float a = bfv[o];
#pragma unroll
        for (int j = 0; j < 30; j++) a = fmaf(m[j], Wf[j * 10 + o], a);
        lg[o] = a;
    }
    float mx = lg[0];
#pragma unroll
    for (int o = 1; o < 10; o++) mx = fmaxf(mx, lg[o]);
    float s = 0.f;
#pragma unroll
    for (int o = 0; o < 10; o++) { lg[o] = __expf(lg[o] - mx); s += lg[o]; }
    float invs = 1.f / s;
#pragma unroll
    for (int o = 0; o < 10; o++) out[(size_t)g * 10 + o] = lg[o] * invs;
}

extern "C" void kernel_launch(void* const* d_in, const int* in_sizes, int n_in,
                              void* d_out, int out_size, void* d_ws, size_t ws_size,
                              hipStream_t stream)
{
    (void)n_in; (void)ws_size;
    const float* x[3]    = {(const float*)d_in[0], (const float*)d_in[1], (const float*)d_in[2]};
    const float* vals[3] = {(const float*)d_in[3], (const float*)d_in[4], (const float*)d_in[5]};
    const int* rows[3]   = {(const int*)d_in[6], (const int*)d_in[8], (const int*)d_in[10]};
    const int* cols[3]   = {(const int*)d_in[7], (const int*)d_in[9], (const int*)d_in[11]};
    const int* batch[3]  = {(const int*)d_in[12], (const int*)d_in[13], (const int*)d_in[14]};
    const float* W1[3] = {(const float*)d_in[16], (const float*)d_in[22], (const float*)d_in[28]};
    const float* b1[3] = {(const float*)d_in[17], (const float*)d_in[23], (const float*)d_in[29]};
    const float* W2[3] = {(const float*)d_in[18], (const float*)d_in[24], (const float*)d_in[30]};
    const float* b2[3] = {(const float*)d_in[19], (const float*)d_in[25], (const float*)d_in[31]};
    const float* W3[3] = {(const float*)d_in[20], (const float*)d_in[26], (const float*)d_in[32]};
    const float* b3[3] = {(const float*)d_in[21], (const float*)d_in[27], (const float*)d_in[33]};
    const float* Wf  = (const float*)d_in[34];
    const float* bfv = (const float*)d_in[35];
    float* out = (float*)d_out;

    int N[3] = {in_sizes[0] / 32, in_sizes[1] / 32, in_sizes[2] / 32};
    int E[3] = {in_sizes[3], in_sizes[4], in_sizes[5]};
    int G = out_size / 10;
    int maxN = N[0]; if (N[1] > maxN) maxN = N[1]; if (N[2] > maxN) maxN = N[2];
    int maxE = E[0]; if (E[1] > maxE) maxE = E[1]; if (E[2] > maxE) maxE = E[2];
    int maxNBm = cdiv(maxN, 1 << MSHIFT);

    float* bufA   = (float*)d_ws;                       // layers; aliases stg1 during build
    float* bufZ   = bufA + (size_t)maxN * 32;           // layers (fp16 Z lives here); aliases stgm during build
    int2*  stg1   = (int2*)bufA;                        // build-phase only
    int2*  stgm   = (int2*)bufZ;                        // build-phase only
    half_t* Zh    = (half_t*)bufZ;                      // fp16 Z view (same region, stride 32 halfs)
    float* pool   = bufZ + (size_t)maxN * 32;
    int2*  ecv    = (int2*)(pool + (size_t)G * 30 + 2); // +2 for int2 alignment
    int*   rowptr = (int*)(ecv + maxE);
    int*   mcnt   = rowptr + (maxN + 1);
    int*   mbase  = mcnt + maxNBm;
    int*   mfront = mbase + (maxNBm + 1);
    int*   ccnt   = mfront + maxNBm;
    int*   cbase  = ccnt + 64;
    int*   cfront = cbase + 66;

    for (int d = 0; d < 3; d++) {
        int n = N[d], e = E[d];
        int NBc = cdiv(n, 1 << CSHIFT);
        int NBm = cdiv(n, 1 << MSHIFT);
        int ntile = cdiv(e, TILE_E);

        // --- coarse split -> mid split -> in-block CSR sort (writes rowptr itself) ---
        zero_i32<<<1, 256, 0, stream>>>(ccnt, 64);
        hist_coarse<<<ntile, 256, 0, stream>>>(rows[d], ccnt, e);
        scan_coarse<<<1, 64, 0, stream>>>(ccnt, cbase, cfront, NBc, e);
        split_coarse<<<ntile, 256, 0, stream>>>(rows[d], cols[d], vals[d], cfront, stg1, e);
        zero_i32<<<cdiv(NBm, 256), 256, 0, stream>>>(mcnt, NBm);
        hist_mid<<<ntile, 256, 0, stream>>>(stg1, cbase, mcnt, e, NBc);
        scan_mid<<<1, 256, 0, stream>>>(mcnt, mbase, mfront, NBm, e);
        split_mid<<<ntile, 256, 0, stream>>>(stg1, cbase, mfront, stgm, e, NBc);
        csr_sort<<<NBm, 256, 0, stream>>>(stgm, mbase, rowptr, ecv, n);

        // --- 3 layers, conflict-free CSR gathers (dual-chain), fp16 Z operand ---
        dense_kernel<32, false><<<cdiv(n, 256), 256, 0, stream>>>(x[d], W1[d], b1[d], bufA, Zh, n);
        gather32<<<cdiv((long long)cdiv(n, 2) * 8, 256), 256, 0, stream>>>(rowptr, ecv, Zh, bufA, n);
        dense_kernel<32, true><<<cdiv(n, 256), 256, 0, stream>>>(bufA, W2[d], b2[d], bufA, Zh, n);
        gather32<<<cdiv((long long)cdiv(n, 2) * 8, 256), 256, 0, stream>>>(rowptr, ecv, Zh, bufA, n);
        dense_kernel<10, true><<<cdiv(n, 256), 256, 0, stream>>>(bufA, W3[d], b3[d], bufA, Zh, n);
        gather10<<<cdiv((long long)cdiv(n, 2) * 8, 256), 256, 0, stream>>>(rowptr, ecv, Zh, bufA, n);
        pool_graph<<<G, 256, 0, stream>>>(bufA, batch[d], pool, n, d * 10);
    }
    final_kernel<<<cdiv(G, 256), 256, 0, stream>>>(pool, Wf, bfv, out, G);
}